// Round 1
// baseline (16.379 us; speedup 1.0000x reference)
//
#include <hip/hip_runtime.h>

// RoutingMaskLayer: inputs [B=64, H=32, W=32, C=512] f32, routing [B=64, 4] f32.
// route[b] = argmax(routing[b,:]) ; out[b,h,w,c] = in[b,h,w, route[b]*128 + c]
// Pure coalesced gather, memory-bound. float4 vectorized, grid-stride.

constexpr int Bn     = 64;
constexpr int Hn     = 32;
constexpr int Wn     = 32;
constexpr int Cn     = 512;
constexpr int ROUTES = 4;
constexpr int RW     = Cn / ROUTES;   // 128 channels out per pixel
constexpr int VPP    = RW / 4;        // 32 float4 per pixel (output)
constexpr int IVPP   = Cn / 4;        // 128 float4 per pixel (input)

__global__ void routing_gather_kernel(const float4* __restrict__ in,
                                      const float*  __restrict__ routing,
                                      float4* __restrict__ out,
                                      int total_vecs) {
    int i = blockIdx.x * blockDim.x + threadIdx.x;
    const int stride = gridDim.x * blockDim.x;
    for (; i < total_vecs; i += stride) {
        const int pixel = i >> 5;          // i / VPP   (VPP == 32)
        const int vc    = i & (VPP - 1);   // i % VPP
        const int b     = pixel >> 10;     // pixel / (H*W) == /1024

        // argmax over 4 routes; strict '>' keeps first-max semantics (jnp.argmax)
        const float4 r = *reinterpret_cast<const float4*>(routing + b * ROUTES);
        int   best = 0;
        float bv   = r.x;
        if (r.y > bv) { bv = r.y; best = 1; }
        if (r.z > bv) { bv = r.z; best = 2; }
        if (r.w > bv) { bv = r.w; best = 3; }

        out[i] = in[pixel * IVPP + best * VPP + vc];
    }
}

extern "C" void kernel_launch(void* const* d_in, const int* in_sizes, int n_in,
                              void* d_out, int out_size, void* d_ws, size_t ws_size,
                              hipStream_t stream) {
    const float4* in      = (const float4*)d_in[0];
    const float*  routing = (const float*)d_in[1];
    float4*       out     = (float4*)d_out;

    const int total_vecs = Bn * Hn * Wn * VPP;  // 2,097,152 float4
    const int block = 256;
    const int grid  = 2048;                     // grid-stride, 4 vecs/thread
    routing_gather_kernel<<<grid, block, 0, stream>>>(in, routing, out, total_vecs);
}

// Round 2
// 15.967 us; speedup vs baseline: 1.0258x; 1.0258x over previous
//
#include <hip/hip_runtime.h>

// RoutingMaskLayer: in [B=64,H=32,W=32,C=512] f32, routing [B=64,4] f32.
// route[b]=argmax(routing[b,:]); out[b,h,w,c]=in[b,h,w, route[b]*128+c]
// Memory-bound gather. Round 1: static unroll-4, all loads before stores (MLP),
// one argmax per thread, block pinned to a single image.

constexpr int Bn     = 64;
constexpr int Hn     = 32;
constexpr int Wn     = 32;
constexpr int Cn     = 512;
constexpr int ROUTES = 4;
constexpr int RW     = Cn / ROUTES;       // 128 out channels / pixel
constexpr int VPP    = RW / 4;            // 32 float4 per pixel (out)
constexpr int TOTAL_VECS = Bn * Hn * Wn * VPP;      // 2,097,152
constexpr int VECS_PER_BLOCK = 1024;                 // 4 per thread * 256
constexpr int BLOCKS = TOTAL_VECS / VECS_PER_BLOCK;  // 2048 (= 8/CU exactly)
constexpr int BLOCKS_PER_IMG = (Hn * Wn * VPP) / VECS_PER_BLOCK;  // 32

__global__ __launch_bounds__(256)
void routing_gather_kernel(const float4* __restrict__ in,
                           const float*  __restrict__ routing,
                           float4* __restrict__ out) {
    const int b = blockIdx.x >> 5;  // blockIdx / BLOCKS_PER_IMG (=32)

    // argmax over 4 routes (strict '>' = jnp.argmax first-max semantics).
    // One 16B L1-broadcast load per wave.
    const float4 r = *reinterpret_cast<const float4*>(routing + b * ROUTES);
    int   best = 0;
    float bv   = r.x;
    if (r.y > bv) { bv = r.y; best = 1; }
    if (r.z > bv) { bv = r.z; best = 2; }
    if (r.w > bv) { bv = r.w; best = 3; }
    const int boff = best << 5;     // best * VPP

    const int base = blockIdx.x * VECS_PER_BLOCK + threadIdx.x;
    const int v0 = base;
    const int v1 = base + 256;
    const int v2 = base + 512;
    const int v3 = base + 768;

    // in vec index for out vec v: (pixel<<7) + best*32 + (v&31), pixel = v>>5
    const int i0 = ((v0 >> 5) << 7) + boff + (v0 & 31);
    const int i1 = ((v1 >> 5) << 7) + boff + (v1 & 31);
    const int i2 = ((v2 >> 5) << 7) + boff + (v2 & 31);
    const int i3 = ((v3 >> 5) << 7) + boff + (v3 & 31);

    // 4 independent loads in flight, then 4 stores.
    const float4 a0 = in[i0];
    const float4 a1 = in[i1];
    const float4 a2 = in[i2];
    const float4 a3 = in[i3];
    out[v0] = a0;
    out[v1] = a1;
    out[v2] = a2;
    out[v3] = a3;
}

extern "C" void kernel_launch(void* const* d_in, const int* in_sizes, int n_in,
                              void* d_out, int out_size, void* d_ws, size_t ws_size,
                              hipStream_t stream) {
    const float4* in      = (const float4*)d_in[0];
    const float*  routing = (const float*)d_in[1];
    float4*       out     = (float4*)d_out;

    routing_gather_kernel<<<BLOCKS, 256, 0, stream>>>(in, routing, out);
}

// Round 4
// 14.013 us; speedup vs baseline: 1.1689x; 1.1395x over previous
//
#include <hip/hip_runtime.h>

// RoutingMaskLayer: in [B=64,H=32,W=32,C=512] f32, routing [B=64,4] f32.
// route[b]=argmax(routing[b,:]); out[b,h,w,c]=in[b,h,w, route[b]*128+c]
// Memory-bound gather. Round 3: nontemporal stores via clang ext_vector
// (HIP float4 class type rejected by the builtin), 2 vecs/thread.

typedef float f32x4 __attribute__((ext_vector_type(4)));

constexpr int Bn     = 64;
constexpr int Hn     = 32;
constexpr int Wn     = 32;
constexpr int Cn     = 512;
constexpr int ROUTES = 4;
constexpr int RW     = Cn / ROUTES;       // 128 out channels / pixel
constexpr int VPP    = RW / 4;            // 32 f32x4 per pixel (out)
constexpr int TOTAL_VECS = Bn * Hn * Wn * VPP;      // 2,097,152
constexpr int VECS_PER_BLOCK = 512;                  // 2 per thread * 256
constexpr int BLOCKS = TOTAL_VECS / VECS_PER_BLOCK;  // 4096
// 4096 blocks / 64 images = 64 blocks per image -> blockIdx>>6 = image

__global__ __launch_bounds__(256)
void routing_gather_kernel(const f32x4* __restrict__ in,
                           const float* __restrict__ routing,
                           f32x4* __restrict__ out) {
    const int b = blockIdx.x >> 6;  // image index (64 blocks/image)

    // argmax over 4 routes (strict '>' = jnp.argmax first-max semantics).
    const f32x4 r = *reinterpret_cast<const f32x4*>(routing + b * ROUTES);
    int   best = 0;
    float bv   = r.x;
    if (r.y > bv) { bv = r.y; best = 1; }
    if (r.z > bv) { bv = r.z; best = 2; }
    if (r.w > bv) { bv = r.w; best = 3; }
    const int boff = best << 5;     // best * VPP

    const int base = blockIdx.x * VECS_PER_BLOCK + threadIdx.x;
    const int v0 = base;
    const int v1 = base + 256;

    // in vec index for out vec v: (pixel<<7) + best*32 + (v&31), pixel = v>>5
    const int i0 = ((v0 >> 5) << 7) + boff + (v0 & 31);
    const int i1 = ((v1 >> 5) << 7) + boff + (v1 & 31);

    const f32x4 a0 = in[i0];
    const f32x4 a1 = in[i1];
    __builtin_nontemporal_store(a0, &out[v0]);
    __builtin_nontemporal_store(a1, &out[v1]);
}

extern "C" void kernel_launch(void* const* d_in, const int* in_sizes, int n_in,
                              void* d_out, int out_size, void* d_ws, size_t ws_size,
                              hipStream_t stream) {
    const f32x4* in      = (const f32x4*)d_in[0];
    const float* routing = (const float*)d_in[1];
    f32x4*       out     = (f32x4*)d_out;

    routing_gather_kernel<<<BLOCKS, 256, 0, stream>>>(in, routing, out);
}